// Round 9
// baseline (87.716 us; speedup 1.0000x reference)
//
#include <hip/hip_runtime.h>
#include <math.h>

#define L 4096
#define JC 16            // j-chunk per block in pair kernel
#define NJB (L/JC)       // 256 j-chunks
#define NIB 4            // i-blocks (1024 i's each: 4 i's per thread)
#define NBLK (NIB*NJB)   // 1024 pair blocks

// AA order 'ACDEFGHIKLMNPQRSTVWYX'
__constant__ float c_charge[21] = {0.f,0.f,-1.f,-1.f,0.f,0.f,0.5f,0.f,1.f,0.f,0.f,0.f,0.f,0.f,1.f,0.f,0.f,0.f,0.f,0.f,0.f};
__constant__ float c_hydro[21]  = {1.8f,2.5f,-3.5f,-3.5f,2.8f,-0.4f,-3.2f,4.5f,-3.9f,3.8f,1.9f,-3.5f,-1.6f,-3.5f,-4.5f,-0.8f,-0.7f,4.2f,-0.9f,-1.3f,0.f};
__constant__ float c_phi0[21]   = {-60.f,-60.f,-60.f,-60.f,-60.f,-75.f,-60.f,-60.f,-60.f,-60.f,-60.f,-60.f,-65.f,-60.f,-60.f,-60.f,-60.f,-60.f,-60.f,-60.f,-60.f};
__constant__ float c_psi0[21]   = {-45.f,-45.f,-45.f,-45.f,-45.f,-60.f,-45.f,-45.f,-45.f,-45.f,-45.f,-45.f,-30.f,-45.f,-45.f,-45.f,-45.f,-45.f,-45.f,-45.f,-45.f};
__constant__ float c_wid[21]    = {25.f,25.f,25.f,25.f,25.f,40.f,25.f,25.f,25.f,25.f,25.f,25.f,20.f,25.f,25.f,25.f,25.f,25.f,25.f,25.f,25.f};

// ws float layout (float4 regions 16B-aligned):
// 0   : PA  [L] float4  (ca.xyz, charge)
// 4L  : PB  [L] float4  (N.xyz, 0)
// 8L  : PI1 [L] float4  (O.xyz, nco)
// 12L : PI2 [L] float4  (vco.xyz, ideal)
// 16L : PI3 [L] float4  (cb.xyz, 0)
// 20L : DENS[L]
// 21L : DMIN[L] (uint bits of squared dist)
// 22L : RP  [5*64]  residue per-wave partials
// 22L+320 : BPel[NBLK], then BPhb[NBLK]
#define WS_PA(ws)   ((float4*)(ws))
#define WS_PB(ws)   ((float4*)((ws)+4*L))
#define WS_PI1(ws)  ((float4*)((ws)+8*L))
#define WS_PI2(ws)  ((float4*)((ws)+12*L))
#define WS_PI3(ws)  ((float4*)((ws)+16*L))
#define WS_DENS(ws) ((ws)+20*L)
#define WS_DMIN(ws) ((unsigned int*)((ws)+21*L))
#define WS_RP(ws)   ((ws)+22*L)
#define WS_BPEL(ws) ((ws)+22*L+320)
#define WS_BPHB(ws) ((ws)+22*L+320+NBLK)

struct f3 { float x, y, z; };
__device__ inline f3 mk(float x, float y, float z){ f3 r{x,y,z}; return r; }
__device__ inline f3 sub3(f3 a, f3 b){ return mk(a.x-b.x, a.y-b.y, a.z-b.z); }
__device__ inline f3 add3(f3 a, f3 b){ return mk(a.x+b.x, a.y+b.y, a.z+b.z); }
__device__ inline f3 scl3(f3 a, float s){ return mk(a.x*s, a.y*s, a.z*s); }
__device__ inline float dot3(f3 a, f3 b){ return a.x*b.x + a.y*b.y + a.z*b.z; }
__device__ inline f3 crs3(f3 a, f3 b){ return mk(a.y*b.z-a.z*b.y, a.z*b.x-a.x*b.z, a.x*b.y-a.y*b.x); }
__device__ inline float nrm3(f3 a){ return sqrtf(dot3(a,a)); }
__device__ inline f3 unit3(f3 a){ float n = fmaxf(nrm3(a), 1e-8f); return mk(a.x/n, a.y/n, a.z/n); }

__device__ inline float dihedral(f3 p0, f3 p1, f3 p2, f3 p3){
  f3 b0 = sub3(p1,p0), b1 = sub3(p2,p1), b2 = sub3(p3,p2);
  f3 b1n = unit3(b1);
  f3 v = sub3(b0, scl3(b1n, dot3(b0,b1n)));
  f3 w = sub3(b2, scl3(b1n, dot3(b2,b1n)));
  float x = dot3(v,w);
  float y = dot3(crs3(b1n,v), w);
  return atan2f(y + 1e-8f, x + 1e-8f);
}

__device__ inline float wave_reduce(float v){
  #pragma unroll
  for (int off = 32; off > 0; off >>= 1) v += __shfl_down(v, off, 64);
  return v;
}

// 64 blocks x 64 threads: one wave per block, i = blk*64+lane
__global__ __launch_bounds__(64) void residue_kernel(const float* __restrict__ ca,
    const float* __restrict__ alpha, const int* __restrict__ seq, float* __restrict__ ws)
{
  int i = blockIdx.x*64 + threadIdx.x;
  f3 c0 = mk(ca[3*i], ca[3*i+1], ca[3*i+2]);
  f3 cm = c0, cp = c0;
  if (i > 0)   cm = mk(ca[3*(i-1)], ca[3*(i-1)+1], ca[3*(i-1)+2]);
  if (i < L-1) cp = mk(ca[3*(i+1)], ca[3*(i+1)+1], ca[3*(i+1)+2]);
  f3 vnm = unit3(sub3(c0, cm));   // vn[i-1] (valid for i>=1)
  f3 vni = unit3(sub3(cp, c0));   // vn[i]   (valid for i<=L-2)

  f3 N = (i == 0)  ? sub3(c0, scl3(vni, 1.45f)) : sub3(c0, scl3(vnm, 1.45f));
  f3 C = (i < L-1) ? add3(c0, scl3(vni, 1.52f)) : add3(c0, scl3(vnm, 1.52f));
  f3 perp = crs3(sub3(C,c0), sub3(N,c0));
  float pn = nrm3(perp);
  if (pn > 1e-6f) perp = scl3(perp, 1.f/fmaxf(pn, 1e-30f));
  f3 O = (i < L-1) ? add3(C, scl3(perp, 1.24f)) : mk(C.x, C.y + 1.24f, C.z);

  f3 sum = add3(sub3(N,c0), sub3(C,c0));
  f3 cbdir = unit3(mk(-sum.x, -sum.y, -sum.z));
  f3 cb = add3(c0, scl3(cbdir, 1.8f));

  f3 vco = sub3(O, C);
  float nco = fmaxf(nrm3(vco), 1e-8f);

  int sid = seq[i];
  float al = alpha[i];

  float4 pa; pa.x=c0.x; pa.y=c0.y; pa.z=c0.z; pa.w=c_charge[sid];
  float4 pb; pb.x=N.x; pb.y=N.y; pb.z=N.z; pb.w=0.f;
  float4 p1; p1.x=O.x; p1.y=O.y; p1.z=O.z; p1.w=nco;
  float4 p2; p2.x=vco.x; p2.y=vco.y; p2.z=vco.z; p2.w=2.9f*(1.f + 0.1f*(al - 1.f));
  float4 p3; p3.x=cb.x; p3.y=cb.y; p3.z=cb.z; p3.w=0.f;
  WS_PA(ws)[i]=pa; WS_PB(ws)[i]=pb; WS_PI1(ws)[i]=p1; WS_PI2(ws)[i]=p2; WS_PI3(ws)[i]=p3;
  WS_DENS(ws)[i]=0.f;
  WS_DMIN(ws)[i]=0x7F800000u;   // +inf

  // ---- O(L) energy terms ----
  float bond = 0.f, angle = 0.f, rama = 0.f, smooth = 0.f;
  float ent = al * logf(al + 1e-8f);
  if (i < L-1) {
    float alp = alpha[i+1];
    float d = nrm3(sub3(cp, c0));
    float tp = 0.5f*(3.8f*(1.f+0.1f*(al-1.f)) + 3.8f*(1.f+0.1f*(alp-1.f)));
    bond = (d - tp)*(d - tp);
    smooth = (alp - al)*(alp - al);
  }
  if (i >= 1 && i <= L-2) {
    f3 v1 = unit3(sub3(cm, c0));
    f3 v2 = unit3(sub3(cp, c0));
    float cang = dot3(v1, v2);
    float ct = cosf(1.5708f*(1.f + 0.1f*(al - 1.f)));
    angle = (cang - ct)*(cang - ct);

    f3 Cm1 = add3(cm, scl3(vnm, 1.52f));   // Catm[i-1]
    f3 Np1 = sub3(cp, scl3(vni, 1.45f));   // Natm[i+1]
    const float deg = 57.29577951308232f;
    float phi = dihedral(Cm1, N, c0, C) * deg;
    float psi = dihedral(N, c0, C, Np1) * deg;
    float weff = c_wid[sid]*(1.f + 0.1f*(al - 1.f)) + 1e-8f;
    float dphi = (phi - c_phi0[sid]) / weff;
    float dpsi = (psi - c_psi0[sid]) / weff;
    rama = dphi*dphi + dpsi*dpsi;
  }
  bond = wave_reduce(bond); angle = wave_reduce(angle); rama = wave_reduce(rama);
  ent  = wave_reduce(ent);  smooth = wave_reduce(smooth);
  if (threadIdx.x == 0) {
    float* RP = WS_RP(ws);
    int b = blockIdx.x;
    RP[0*64+b]=bond; RP[1*64+b]=angle; RP[2*64+b]=rama; RP[3*64+b]=ent; RP[4*64+b]=smooth;
  }
}

// grid (4,256), 256 threads; each thread handles i = bx*1024 + t + {0,256,512,768}
__global__ __launch_bounds__(256) void pair_kernel(float* __restrict__ ws)
{
  const float4* __restrict__ PA  = WS_PA(ws);
  const float4* __restrict__ PB  = WS_PB(ws);
  const float4* __restrict__ PI1 = WS_PI1(ws);
  const float4* __restrict__ PI2 = WS_PI2(ws);
  const float4* __restrict__ PI3 = WS_PI3(ws);

  int t = threadIdx.x;
  int ibase = blockIdx.x*1024 + t;
  int j0 = blockIdx.y*JC;

  __shared__ float4 sA[JC];   // ca.xyz, q
  __shared__ float4 sB[JC];   // N.xyz, -
  if (t < JC)           sA[t]     = PA[j0 + t];
  else if (t < 2*JC)    sB[t-JC]  = PB[j0 + t - JC];

  const int i0 = ibase, i1 = ibase+256, i2 = ibase+512, i3 = ibase+768;
  float4 a0 = PA[i0],  a1 = PA[i1],  a2 = PA[i2],  a3 = PA[i3];
  float4 o0 = PI1[i0], o1 = PI1[i1], o2 = PI1[i2], o3 = PI1[i3];
  float4 w0 = PI2[i0], w1 = PI2[i1], w2 = PI2[i2], w3 = PI2[i3];
  float4 g0 = PI3[i0], g1 = PI3[i1], g2 = PI3[i2], g3 = PI3[i3];
  float rn0 = __builtin_amdgcn_rcpf(o0.w), rn1 = __builtin_amdgcn_rcpf(o1.w);
  float rn2 = __builtin_amdgcn_rcpf(o2.w), rn3 = __builtin_amdgcn_rcpf(o3.w);
  __syncthreads();

  float e_el = 0.f, e_hb = 0.f;
  float dens0=0.f, dens1=0.f, dens2=0.f, dens3=0.f;
  float dm0=3.0e38f, dm1=3.0e38f, dm2=3.0e38f, dm3=3.0e38f;

  #pragma unroll
  for (int jj = 0; jj < JC; ++jj) {
    float4 a = sA[jj];
    float4 b = sB[jj];
    int jg = j0 + jj;

#define CA_DIST(K) \
    float dx##K = a##K.x - a.x, dy##K = a##K.y - a.y, dz##K = a##K.z - a.z; \
    float d2##K = fmaf(dx##K,dx##K, fmaf(dy##K,dy##K, dz##K*dz##K)); \
    dens##K += (d2##K < 100.f) ? 1.f : 0.f;
    CA_DIST(0) CA_DIST(1) CA_DIST(2) CA_DIST(3)
#undef CA_DIST

#define CB_MIN(K) { \
    float rx = g##K.x - a.x, ry = g##K.y - a.y, rz = g##K.z - a.z; \
    float r2 = fmaf(rx,rx, fmaf(ry,ry, rz*rz)); \
    dm##K = fminf(dm##K, (jg == i##K) ? 3.0e38f : r2); }
    CB_MIN(0) CB_MIN(1) CB_MIN(2) CB_MIN(3)
#undef CB_MIN

    if (a.w != 0.f) {   // wave-uniform: ~24% of j's are charged
#define ELEC(K) { \
      float qq = (jg == i##K) ? 0.f : a##K.w * a.w; \
      float D  = sqrtf(d2##K) + 1e-6f; \
      e_el += qq * __expf(-0.1f*D) * __builtin_amdgcn_rcpf(80.f*D); }
      ELEC(0) ELEC(1) ELEC(2) ELEC(3)
#undef ELEC
    }

#define HB(K) { \
    float nx = b.x - o##K.x, ny = b.y - o##K.y, nz = b.z - o##K.z; \
    float h2 = fmaf(nx,nx, fmaf(ny,ny, nz*nz)); \
    if (h2 > 6.25f && h2 < 12.25f) { \
      float rs  = __builtin_amdgcn_rsqf(h2); \
      float Dh  = h2 * rs; \
      float num = fmaf(w##K.x,nx, fmaf(w##K.y,ny, w##K.z*nz)); \
      float tt  = (Dh - w##K.w) * 3.33333333333333f; \
      e_hb -= num * (rn##K * rs) * __expf(-tt*tt); } }
    HB(0) HB(1) HB(2) HB(3)
#undef HB
  }

  e_el = wave_reduce(e_el);
  e_hb = wave_reduce(e_hb);
  __shared__ float sp[8];
  if ((t & 63) == 0) { sp[t>>6] = e_el; sp[4+(t>>6)] = e_hb; }
  __syncthreads();
  if (t == 0) {
    int bidx = blockIdx.y*NIB + blockIdx.x;
    WS_BPEL(ws)[bidx] = sp[0]+sp[1]+sp[2]+sp[3];
    WS_BPHB(ws)[bidx] = sp[4]+sp[5]+sp[6]+sp[7];
  }
  atomicAdd(&WS_DENS(ws)[i0], dens0);
  atomicAdd(&WS_DENS(ws)[i1], dens1);
  atomicAdd(&WS_DENS(ws)[i2], dens2);
  atomicAdd(&WS_DENS(ws)[i3], dens3);
  atomicMin(&WS_DMIN(ws)[i0], __float_as_uint(dm0));
  atomicMin(&WS_DMIN(ws)[i1], __float_as_uint(dm1));
  atomicMin(&WS_DMIN(ws)[i2], __float_as_uint(dm2));
  atomicMin(&WS_DMIN(ws)[i3], __float_as_uint(dm3));
}

// single block, 1024 threads: sum partials + solvent/rotamer + combine
__global__ __launch_bounds__(1024) void final_kernel(const int* __restrict__ seq,
    const float* __restrict__ ws, float* __restrict__ out)
{
  int t = threadIdx.x;
  const float* BPel = WS_BPEL(ws);
  const float* BPhb = WS_BPHB(ws);
  const float* RP = WS_RP(ws);

  float v0=0.f,v1=0.f,v2=0.f,v3=0.f,v4=0.f,v7=0.f,v8=0.f;
  float v5 = BPel[t];   // NBLK == 1024 == blockDim
  float v6 = BPhb[t];
  if (t < 64) { v0=RP[t]; v1=RP[64+t]; v2=RP[128+t]; v3=RP[192+t]; v4=RP[256+t]; }

  #pragma unroll
  for (int k = 0; k < 4; ++k) {
    int i = t + k*1024;
    float density = WS_DENS((float*)ws)[i];
    float burial = 1.f - __expf(-density * 0.05f);
    float hy = c_hydro[seq[i]];
    v7 += (hy > 0.f) ? hy*(1.f - burial) : (-hy*burial);
    float dmin = sqrtf(__uint_as_float(((const unsigned int*)(ws+21*L))[i]));
    if (seq[i] != 5 && i > 0 && i < L-1) v8 += fmaxf(4.f - dmin, 0.f);
  }

  v0=wave_reduce(v0); v1=wave_reduce(v1); v2=wave_reduce(v2);
  v3=wave_reduce(v3); v4=wave_reduce(v4); v5=wave_reduce(v5);
  v6=wave_reduce(v6); v7=wave_reduce(v7); v8=wave_reduce(v8);

  __shared__ float red[16*9];
  int w = t >> 6;
  if ((t & 63) == 0) {
    red[w*9+0]=v0; red[w*9+1]=v1; red[w*9+2]=v2; red[w*9+3]=v3; red[w*9+4]=v4;
    red[w*9+5]=v5; red[w*9+6]=v6; red[w*9+7]=v7; red[w*9+8]=v8;
  }
  __syncthreads();
  if (t == 0) {
    float s[9];
    #pragma unroll
    for (int q = 0; q < 9; ++q) s[q] = 0.f;
    for (int ww = 0; ww < 16; ++ww)
      #pragma unroll
      for (int q = 0; q < 9; ++q) s[q] += red[ww*9+q];
    const float Lf = (float)L;
    out[0] = s[0] / (Lf - 1.f)            // bond
           + s[1] / (Lf - 2.f)            // angle
           + 0.5f * s[2] / (Lf - 2.f)     // rama
           + 0.5f * s[5] / (Lf * Lf)      // electro
           + s[6] / (Lf * Lf)             // hbond
           + 0.5f * s[7] / Lf             // solvent
           + 0.5f * s[8] / (Lf - 2.f)     // rotamer
           + 0.01f * (-s[3] / Lf)         // entropy
           + 0.01f * s[4] / (Lf - 1.f);   // smooth
  }
}

extern "C" void kernel_launch(void* const* d_in, const int* in_sizes, int n_in,
                              void* d_out, int out_size, void* d_ws, size_t ws_size,
                              hipStream_t stream) {
  (void)in_sizes; (void)n_in; (void)out_size; (void)ws_size;
  const float* ca    = (const float*)d_in[0];
  const float* alpha = (const float*)d_in[1];
  const int*   seq   = (const int*)d_in[2];
  float* out = (float*)d_out;
  float* ws  = (float*)d_ws;

  residue_kernel<<<64, 64, 0, stream>>>(ca, alpha, seq, ws);
  pair_kernel<<<dim3(NIB, NJB), 256, 0, stream>>>(ws);
  final_kernel<<<1, 1024, 0, stream>>>(seq, ws, out);
}